// Round 1
// baseline (170.415 us; speedup 1.0000x reference)
//
#include <hip/hip_runtime.h>
#include <cstdint>
#include <cstddef>

// ---------- types ----------
typedef __bf16 bf16;
typedef __attribute__((ext_vector_type(8))) __bf16 bf16x8;
typedef __attribute__((ext_vector_type(4))) float f32x4;

#define MFMA16(a, b, c) __builtin_amdgcn_mfma_f32_16x16x32_bf16((a), (b), (c), 0, 0, 0)

// Problem constants (BertSelfAttentionMem: B=2, S=2048, HIDDEN=1024, H=16, D=64)
static constexpr int BB   = 2;
static constexpr int SS   = 2048;
static constexpr int HID  = 1024;
static constexpr int NH   = 16;
static constexpr int HD   = 64;
static constexpr int MROW = BB * SS;     // 4096
static constexpr int NQKV = 3 * HID;     // 3072

// ---------- kernel 1: fp32 -> bf16 convert (vectorized) ----------
__global__ __launch_bounds__(256) void cvt_hidden(const float* __restrict__ in,
                                                  bf16* __restrict__ out) {
    const int i = (blockIdx.x * 256 + threadIdx.x) * 8;
    float4 f0 = *(const float4*)&in[i];
    float4 f1 = *(const float4*)&in[i + 4];
    bf16x8 o;
    o[0] = (bf16)f0.x; o[1] = (bf16)f0.y; o[2] = (bf16)f0.z; o[3] = (bf16)f0.w;
    o[4] = (bf16)f1.x; o[5] = (bf16)f1.y; o[6] = (bf16)f1.z; o[7] = (bf16)f1.w;
    *(bf16x8*)&out[i] = o;
}

// ---------- kernel 2: transpose-convert W [1024][1024] f32 -> Wt [n][k] bf16 ----------
// blockIdx.z selects Wq/Wk/Wv; output rows n are the fused 3072-wide N dim.
__global__ __launch_bounds__(256) void wtrans(const float* __restrict__ Wq,
                                              const float* __restrict__ Wk,
                                              const float* __restrict__ Wv,
                                              bf16* __restrict__ Wt) {
    __shared__ float tile[32][33];
    const float* W = (blockIdx.z == 0) ? Wq : (blockIdx.z == 1) ? Wk : Wv;
    bf16* O = Wt + (size_t)blockIdx.z * HID * HID;
    const int x  = blockIdx.x * 32 + threadIdx.x;  // n
    const int y0 = blockIdx.y * 32;                // k
#pragma unroll
    for (int i = threadIdx.y; i < 32; i += 8)
        tile[i][threadIdx.x] = W[(size_t)(y0 + i) * HID + x];
    __syncthreads();
    const int k = y0 + threadIdx.x;
#pragma unroll
    for (int i = threadIdx.y; i < 32; i += 8)
        O[(size_t)(blockIdx.x * 32 + i) * HID + k] = (bf16)tile[threadIdx.x][i];
}

// ---------- kernel 3: QKV GEMM ----------
// C[m][n] = A[m][k] * Bt[n][k]^T, M=4096 N=3072 K=1024, bf16 MFMA 16x16x32.
// 128x128 tile, 4 waves (2x2), BK=32, register staging, 2 barriers/K-step.
// Epilogue: +bias, Q pre-scaled by 0.125, scatter to [B,H,S,D] bf16.
__global__ __launch_bounds__(256) void qkv_gemm(
    const bf16* __restrict__ A, const bf16* __restrict__ Bt,
    const float* __restrict__ bq, const float* __restrict__ bk,
    const float* __restrict__ bv,
    bf16* __restrict__ Qo, bf16* __restrict__ Ko, bf16* __restrict__ Vo) {
    __shared__ __align__(16) bf16 As[128 * 32];
    __shared__ __align__(16) bf16 Bs[128 * 32];
    const int t = threadIdx.x, l = t & 63, w = t >> 6;
    const int l15 = l & 15, l4 = l >> 4;
    const int wm = w >> 1, wn = w & 1;
    const int m0 = blockIdx.y * 128, n0 = blockIdx.x * 128;

    f32x4 acc[4][4] = {};

    for (int kt = 0; kt < 32; ++kt) {
        const int k0 = kt * 32;
        __syncthreads();
        // stage A,B tiles: 512 chunks of 16B each; linear LDS layout [row][32]
#pragma unroll
        for (int cc = 0; cc < 2; ++cc) {
            const int c = t + cc * 256;
            const int row = c >> 2, col = (c & 3) * 8;
            *(bf16x8*)((char*)As + c * 16) =
                *(const bf16x8*)&A[(size_t)(m0 + row) * HID + k0 + col];
            *(bf16x8*)((char*)Bs + c * 16) =
                *(const bf16x8*)&Bt[(size_t)(n0 + row) * HID + k0 + col];
        }
        __syncthreads();

        bf16x8 af[4], bf_[4];
#pragma unroll
        for (int mi = 0; mi < 4; ++mi) {
            const int r = wm * 64 + mi * 16 + l15;
            af[mi] = *(const bf16x8*)((const char*)As + r * 64 + l4 * 16);
        }
#pragma unroll
        for (int ni = 0; ni < 4; ++ni) {
            const int r = wn * 64 + ni * 16 + l15;
            bf_[ni] = *(const bf16x8*)((const char*)Bs + r * 64 + l4 * 16);
        }
#pragma unroll
        for (int mi = 0; mi < 4; ++mi)
#pragma unroll
            for (int ni = 0; ni < 4; ++ni)
                acc[mi][ni] = MFMA16(af[mi], bf_[ni], acc[mi][ni]);
    }

    // epilogue: C/D layout col=l&15, row=(l>>4)*4+j (HW-verified)
#pragma unroll
    for (int mi = 0; mi < 4; ++mi) {
#pragma unroll
        for (int ni = 0; ni < 4; ++ni) {
            const int ng = n0 + wn * 64 + ni * 16 + l15;
            const int qkv = ng >> 10;          // uniform across the 16-lane group
            const int nn = ng & 1023;
            const int hh = nn >> 6, dd = nn & 63;
            const float* bp = (qkv == 0) ? bq : (qkv == 1) ? bk : bv;
            bf16* op = (qkv == 0) ? Qo : (qkv == 1) ? Ko : Vo;
            const float bias = bp[nn];
            const float scl = (qkv == 0) ? 0.125f : 1.0f;  // fold 1/sqrt(64) into Q
            const int mg = m0 + wm * 64 + mi * 16 + l4 * 4;
            const int bb = mg >> 11, ss = mg & 2047;
            bf16* dst = op + ((size_t)(bb * NH + hh) * SS + ss) * HD + dd;
#pragma unroll
            for (int j = 0; j < 4; ++j)
                dst[(size_t)j * HD] = (bf16)((acc[mi][ni][j] + bias) * scl);
        }
    }
}

// ---------- kernel 4: flash attention ----------
// grid (16 q-tiles, 32 bh). 4 waves x 32 q-rows. KBLK=64.
// K-tile + V^T-tile in LDS (XOR-swizzled 16B slots; rows are 128B -> would be
// 16-way conflicted unswizzled). P re-layout through wave-private swizzled LDS.
__global__ __launch_bounds__(256) void attn_fwd(
    const bf16* __restrict__ Q, const bf16* __restrict__ K,
    const bf16* __restrict__ V, const float* __restrict__ mask,
    float* __restrict__ out) {
    __shared__ __align__(16) char KsB[64 * 128];       // K[key][d]   8 KB
    __shared__ __align__(16) char VtB[64 * 128];       // V^T[d][key] 8 KB
    __shared__ __align__(16) char PsB[4 * 32 * 128];   // per-wave P 16 KB

    const int t = threadIdx.x, l = t & 63, w = t >> 6;
    const int l15 = l & 15, l4 = l >> 4;
    const int bh = blockIdx.y, b = bh >> 4, h = bh & 15;
    const int q0 = blockIdx.x * 128 + w * 32;
    const bf16* Qp = Q + (size_t)bh * SS * HD;
    const bf16* Kp = K + (size_t)bh * SS * HD;
    const bf16* Vp = V + (size_t)bh * SS * HD;
    const float* mkp = mask + b * SS;
    char* myPs = PsB + w * 32 * 128;

    // Q fragments in registers (Q is pre-scaled by 1/8)
    bf16x8 aq[2][2];
#pragma unroll
    for (int rs = 0; rs < 2; ++rs)
#pragma unroll
        for (int kd = 0; kd < 2; ++kd)
            aq[rs][kd] =
                *(const bf16x8*)&Qp[(size_t)(q0 + rs * 16 + l15) * HD + kd * 32 + l4 * 8];

    float mrow[8], lrow[8];
    f32x4 o[2][4] = {};
#pragma unroll
    for (int r = 0; r < 8; ++r) { mrow[r] = -1e30f; lrow[r] = 0.f; }

    for (int kt = 0; kt < SS / 64; ++kt) {
        const int key0 = kt * 64;
        __syncthreads();  // previous tile fully consumed
        // ---- stage K tile (512 x 16B chunks, swizzled) ----
#pragma unroll
        for (int cc = 0; cc < 2; ++cc) {
            const int c = t + cc * 256;
            const int row = c >> 3, col8 = c & 7;
            bf16x8 vv = *(const bf16x8*)&Kp[(size_t)(key0 + row) * HD + col8 * 8];
            *(bf16x8*)(KsB + row * 128 + ((col8 * 16) ^ ((row & 7) << 4))) = vv;
        }
        // ---- stage V^T tile ----
        {
            const int kv = t >> 2, db = (t & 3) * 16;
            bf16x8 v0 = *(const bf16x8*)&Vp[(size_t)(key0 + kv) * HD + db];
            bf16x8 v1 = *(const bf16x8*)&Vp[(size_t)(key0 + kv) * HD + db + 8];
#pragma unroll
            for (int i = 0; i < 8; ++i) {
                const int d0 = db + i, d1 = db + 8 + i;
                *(bf16*)(VtB + d0 * 128 + ((kv * 2) ^ ((d0 & 7) << 4))) = v0[i];
                *(bf16*)(VtB + d1 * 128 + ((kv * 2) ^ ((d1 & 7) << 4))) = v1[i];
            }
        }
        __syncthreads();

        // ---- S = Q K^T (pre-scaled) ----
        f32x4 s[2][4] = {};
#pragma unroll
        for (int kd = 0; kd < 2; ++kd) {
            bf16x8 bk_[4];
#pragma unroll
            for (int ns = 0; ns < 4; ++ns) {
                const int row = ns * 16 + l15;
                bk_[ns] = *(const bf16x8*)(KsB + row * 128 +
                                           ((kd * 64 + l4 * 16) ^ ((row & 7) << 4)));
            }
#pragma unroll
            for (int rs = 0; rs < 2; ++rs)
#pragma unroll
                for (int ns = 0; ns < 4; ++ns)
                    s[rs][ns] = MFMA16(aq[rs][kd], bk_[ns], s[rs][ns]);
        }
        // ---- additive mask ----
        float mk[4];
#pragma unroll
        for (int ns = 0; ns < 4; ++ns) mk[ns] = mkp[key0 + ns * 16 + l15];
#pragma unroll
        for (int rs = 0; rs < 2; ++rs)
#pragma unroll
            for (int ns = 0; ns < 4; ++ns)
#pragma unroll
                for (int j = 0; j < 4; ++j) s[rs][ns][j] += mk[ns];

        // ---- online softmax (rows spread over regs; cols over 16-lane groups) ----
        float pscale[8];
#pragma unroll
        for (int rs = 0; rs < 2; ++rs) {
#pragma unroll
            for (int j = 0; j < 4; ++j) {
                const int r = rs * 4 + j;
                float tm = fmaxf(fmaxf(s[rs][0][j], s[rs][1][j]),
                                 fmaxf(s[rs][2][j], s[rs][3][j]));
                tm = fmaxf(tm, __shfl_xor(tm, 1));
                tm = fmaxf(tm, __shfl_xor(tm, 2));
                tm = fmaxf(tm, __shfl_xor(tm, 4));
                tm = fmaxf(tm, __shfl_xor(tm, 8));
                const float mnew = fmaxf(mrow[r], tm);
                const float sc = __expf(mrow[r] - mnew);
                mrow[r] = mnew;
                pscale[r] = sc;
                float ps = 0.f;
#pragma unroll
                for (int ns = 0; ns < 4; ++ns) {
                    const float p = __expf(s[rs][ns][j] - mnew);
                    s[rs][ns][j] = p;
                    ps += p;
                }
                ps += __shfl_xor(ps, 1);
                ps += __shfl_xor(ps, 2);
                ps += __shfl_xor(ps, 4);
                ps += __shfl_xor(ps, 8);
                lrow[r] = lrow[r] * sc + ps;
            }
        }
        // ---- rescale O ----
#pragma unroll
        for (int rs = 0; rs < 2; ++rs)
#pragma unroll
            for (int ds = 0; ds < 4; ++ds)
#pragma unroll
                for (int j = 0; j < 4; ++j) o[rs][ds][j] *= pscale[rs * 4 + j];

        // ---- P -> wave-private LDS (bf16, swizzled) ----
#pragma unroll
        for (int rs = 0; rs < 2; ++rs)
#pragma unroll
            for (int ns = 0; ns < 4; ++ns)
#pragma unroll
                for (int j = 0; j < 4; ++j) {
                    const int row = rs * 16 + l4 * 4 + j, col = ns * 16 + l15;
                    *(bf16*)(myPs + row * 128 + ((col * 2) ^ ((row & 7) << 4))) =
                        (bf16)s[rs][ns][j];
                }
        // ---- O += P V ----
#pragma unroll
        for (int ks2 = 0; ks2 < 2; ++ks2) {
            bf16x8 pa[2], bv_[4];
#pragma unroll
            for (int rs = 0; rs < 2; ++rs) {
                const int row = rs * 16 + l15;
                pa[rs] = *(const bf16x8*)(myPs + row * 128 +
                                          ((ks2 * 64 + l4 * 16) ^ ((row & 7) << 4)));
            }
#pragma unroll
            for (int ds = 0; ds < 4; ++ds) {
                const int row = ds * 16 + l15;
                bv_[ds] = *(const bf16x8*)(VtB + row * 128 +
                                           ((ks2 * 64 + l4 * 16) ^ ((row & 7) << 4)));
            }
#pragma unroll
            for (int rs = 0; rs < 2; ++rs)
#pragma unroll
                for (int ds = 0; ds < 4; ++ds)
                    o[rs][ds] = MFMA16(pa[rs], bv_[ds], o[rs][ds]);
        }
    }

    // ---- epilogue: O / l, write fp32 [B,S,HID] ----
#pragma unroll
    for (int rs = 0; rs < 2; ++rs) {
#pragma unroll
        for (int j = 0; j < 4; ++j) {
            const int r = rs * 4 + j;
            const float inv = 1.0f / lrow[r];
            const int qrow = q0 + rs * 16 + l4 * 4 + j;
#pragma unroll
            for (int ds = 0; ds < 4; ++ds) {
                const int d = ds * 16 + l15;
                out[(size_t)(b * SS + qrow) * HID + h * HD + d] = o[rs][ds][j] * inv;
            }
        }
    }
}

// ---------- launch ----------
extern "C" void kernel_launch(void* const* d_in, const int* in_sizes, int n_in,
                              void* d_out, int out_size, void* d_ws, size_t ws_size,
                              hipStream_t stream) {
    (void)in_sizes; (void)n_in; (void)out_size; (void)ws_size;
    const float* hs  = (const float*)d_in[0];
    const float* msk = (const float*)d_in[1];
    const float* Wq  = (const float*)d_in[2];
    const float* bq  = (const float*)d_in[3];
    const float* Wk  = (const float*)d_in[4];
    const float* bk  = (const float*)d_in[5];
    const float* Wv  = (const float*)d_in[6];
    const float* bv  = (const float*)d_in[7];
    float* out = (float*)d_out;
    char* ws = (char*)d_ws;

    bf16* Xb = (bf16*)ws;                          // 8 MB  [4096][1024]
    bf16* Wt = (bf16*)(ws + ((size_t)8 << 20));    // 6 MB  [3072][1024]
    bf16* Qb = (bf16*)(ws + ((size_t)14 << 20));   // 8 MB  [B,H,S,D]
    bf16* Kb = (bf16*)(ws + ((size_t)22 << 20));   // 8 MB
    bf16* Vb = (bf16*)(ws + ((size_t)30 << 20));   // 8 MB

    cvt_hidden<<<dim3(MROW * HID / (256 * 8)), dim3(256), 0, stream>>>(hs, Xb);
    wtrans<<<dim3(32, 32, 3), dim3(32, 8), 0, stream>>>(Wq, Wk, Wv, Wt);
    qkv_gemm<<<dim3(NQKV / 128, MROW / 128), dim3(256), 0, stream>>>(
        Xb, Wt, bq, bk, bv, Qb, Kb, Vb);
    attn_fwd<<<dim3(SS / 128, BB * NH), dim3(256), 0, stream>>>(Qb, Kb, Vb, msk, out);
}

// Round 2
// 142.997 us; speedup vs baseline: 1.1917x; 1.1917x over previous
//
#include <hip/hip_runtime.h>
#include <cstdint>
#include <cstddef>

// ---------- types ----------
typedef __bf16 bf16;
typedef __attribute__((ext_vector_type(8))) __bf16 bf16x8;
typedef __attribute__((ext_vector_type(4))) float f32x4;

#define MFMA16(a, b, c) __builtin_amdgcn_mfma_f32_16x16x32_bf16((a), (b), (c), 0, 0, 0)

// Problem constants (BertSelfAttentionMem: B=2, S=2048, HIDDEN=1024, H=16, D=64)
static constexpr int BB   = 2;
static constexpr int SS   = 2048;
static constexpr int HID  = 1024;
static constexpr int NH   = 16;
static constexpr int HD   = 64;
static constexpr int MROW = BB * SS;     // 4096
static constexpr int NQKV = 3 * HID;     // 3072

// XOR swizzle on 16B slots; (r^(r>>3)) spreads both row%8 and row/8 so
// staging writes with row-stride-8 don't alias banks.
__device__ __forceinline__ int SW(int r) { return ((r ^ (r >> 3)) & 7) << 4; }

__device__ __forceinline__ uint32_t pack_bf16(float a, float b) {
    union { bf16 h[2]; uint32_t u; } x;
    x.h[0] = (bf16)a; x.h[1] = (bf16)b;
    return x.u;
}

// ---------- kernel 1: fp32 -> bf16 convert (vectorized) ----------
__global__ __launch_bounds__(256) void cvt_hidden(const float* __restrict__ in,
                                                  bf16* __restrict__ out) {
    const int i = (blockIdx.x * 256 + threadIdx.x) * 8;
    float4 f0 = *(const float4*)&in[i];
    float4 f1 = *(const float4*)&in[i + 4];
    bf16x8 o;
    o[0] = (bf16)f0.x; o[1] = (bf16)f0.y; o[2] = (bf16)f0.z; o[3] = (bf16)f0.w;
    o[4] = (bf16)f1.x; o[5] = (bf16)f1.y; o[6] = (bf16)f1.z; o[7] = (bf16)f1.w;
    *(bf16x8*)&out[i] = o;
}

// ---------- kernel 2: transpose-convert W [1024][1024] f32 -> Wt [n][k] bf16 ----------
__global__ __launch_bounds__(256) void wtrans(const float* __restrict__ Wq,
                                              const float* __restrict__ Wk,
                                              const float* __restrict__ Wv,
                                              bf16* __restrict__ Wt) {
    __shared__ float tile[32][33];
    const float* W = (blockIdx.z == 0) ? Wq : (blockIdx.z == 1) ? Wk : Wv;
    bf16* O = Wt + (size_t)blockIdx.z * HID * HID;
    const int x  = blockIdx.x * 32 + threadIdx.x;  // n
    const int y0 = blockIdx.y * 32;                // k
#pragma unroll
    for (int i = threadIdx.y; i < 32; i += 8)
        tile[i][threadIdx.x] = W[(size_t)(y0 + i) * HID + x];
    __syncthreads();
    const int k = y0 + threadIdx.x;
#pragma unroll
    for (int i = threadIdx.y; i < 32; i += 8)
        O[(size_t)(blockIdx.x * 32 + i) * HID + k] = (bf16)tile[threadIdx.x][i];
}

// ---------- kernel 3: QKV GEMM (unchanged from R1 — passes, ~900 TF class) ----------
__global__ __launch_bounds__(256) void qkv_gemm(
    const bf16* __restrict__ A, const bf16* __restrict__ Bt,
    const float* __restrict__ bq, const float* __restrict__ bk,
    const float* __restrict__ bv,
    bf16* __restrict__ Qo, bf16* __restrict__ Ko, bf16* __restrict__ Vo) {
    __shared__ __align__(16) bf16 As[128 * 32];
    __shared__ __align__(16) bf16 Bs[128 * 32];
    const int t = threadIdx.x, l = t & 63, w = t >> 6;
    const int l15 = l & 15, l4 = l >> 4;
    const int wm = w >> 1, wn = w & 1;
    const int m0 = blockIdx.y * 128, n0 = blockIdx.x * 128;

    f32x4 acc[4][4] = {};

    for (int kt = 0; kt < 32; ++kt) {
        const int k0 = kt * 32;
        __syncthreads();
#pragma unroll
        for (int cc = 0; cc < 2; ++cc) {
            const int c = t + cc * 256;
            const int row = c >> 2, col = (c & 3) * 8;
            *(bf16x8*)((char*)As + c * 16) =
                *(const bf16x8*)&A[(size_t)(m0 + row) * HID + k0 + col];
            *(bf16x8*)((char*)Bs + c * 16) =
                *(const bf16x8*)&Bt[(size_t)(n0 + row) * HID + k0 + col];
        }
        __syncthreads();

        bf16x8 af[4], bf_[4];
#pragma unroll
        for (int mi = 0; mi < 4; ++mi) {
            const int r = wm * 64 + mi * 16 + l15;
            af[mi] = *(const bf16x8*)((const char*)As + r * 64 + l4 * 16);
        }
#pragma unroll
        for (int ni = 0; ni < 4; ++ni) {
            const int r = wn * 64 + ni * 16 + l15;
            bf_[ni] = *(const bf16x8*)((const char*)Bs + r * 64 + l4 * 16);
        }
#pragma unroll
        for (int mi = 0; mi < 4; ++mi)
#pragma unroll
            for (int ni = 0; ni < 4; ++ni)
                acc[mi][ni] = MFMA16(af[mi], bf_[ni], acc[mi][ni]);
    }

#pragma unroll
    for (int mi = 0; mi < 4; ++mi) {
#pragma unroll
        for (int ni = 0; ni < 4; ++ni) {
            const int ng = n0 + wn * 64 + ni * 16 + l15;
            const int qkv = ng >> 10;
            const int nn = ng & 1023;
            const int hh = nn >> 6, dd = nn & 63;
            const float* bp = (qkv == 0) ? bq : (qkv == 1) ? bk : bv;
            bf16* op = (qkv == 0) ? Qo : (qkv == 1) ? Ko : Vo;
            const float bias = bp[nn];
            const float scl = (qkv == 0) ? 0.125f : 1.0f;  // fold 1/sqrt(64) into Q
            const int mg = m0 + wm * 64 + mi * 16 + l4 * 4;
            const int bb = mg >> 11, ss = mg & 2047;
            bf16* dst = op + ((size_t)(bb * NH + hh) * SS + ss) * HD + dd;
#pragma unroll
            for (int j = 0; j < 4; ++j)
                dst[(size_t)j * HD] = (bf16)((acc[mi][ni][j] + bias) * scl);
        }
    }
}

// ---------- kernel 4: flash attention v2 (swapped QK^T, in-register P) ----------
// Grid: 1024 blocks (XCD-remapped; 1024 = 8*128 exactly -> bijective), 4 waves.
// Block = 64 q-rows (wave = 16), KBLK = 64. LDS = K tile + V^T tile (16 KB).
// Swapped S^T = mfma(K, Q): lane owns ONE query (q = l&15), 16 keys
// (ns*16 + l4*4 + j). Softmax = in-lane reduce + shfl_xor(16,32).
// P -> PV A-frag via 16 bpermutes + 8 selects (no LDS round-trip).
__global__ __launch_bounds__(256) void attn_fwd(
    const bf16* __restrict__ Q, const bf16* __restrict__ K,
    const bf16* __restrict__ V, const float* __restrict__ mask,
    float* __restrict__ out) {
    __shared__ __align__(16) char KsB[64 * 128];   // K[key][d]   8 KB, SW-swizzled
    __shared__ __align__(16) char VtB[64 * 128];   // V^T[d][key] 8 KB, SW-swizzled

    const int t = threadIdx.x, l = t & 63, w = t >> 6;
    const int l15 = l & 15, l4 = l >> 4;

    // XCD-aware remap: each XCD owns 4 consecutive bh (K/V fits its L2)
    const int bid = blockIdx.x;
    const int nid = (bid & 7) * 128 + (bid >> 3);
    const int bh = nid >> 5, qb = nid & 31;
    const int b = bh >> 4, h = bh & 15;
    const int q0 = qb * 64 + w * 16;

    const bf16* Qp = Q + (size_t)bh * SS * HD;
    const bf16* Kp = K + (size_t)bh * SS * HD;
    const bf16* Vp = V + (size_t)bh * SS * HD;
    const float* mkp = mask + b * SS;

    // Q as B-operand fragments: lane supplies Q[q0+l15][kd*32 + l4*8 + c]
    bf16x8 qf[2];
#pragma unroll
    for (int kd = 0; kd < 2; ++kd)
        qf[kd] = *(const bf16x8*)&Qp[(size_t)(q0 + l15) * HD + kd * 32 + l4 * 8];

    float mrun = -1e30f, lrun = 0.f;
    f32x4 o[4] = {};

    // V^T staging assignment: key-pair p = t>>3, d-block = (t&7)*8 (coalesced loads)
    const int vp_ = t >> 3;
    const int vdb = (t & 7) * 8;
    const int src0 = l15 + ((l & 16) ? 32 : 0);  // l15 + 32*(l4&1)
    const bool hi = (l4 & 2) != 0;               // selects ns = 2ks+1

    for (int kt = 0; kt < SS / 64; ++kt) {
        const int key0 = kt * 64;
        __syncthreads();  // previous tile fully consumed
        // ---- stage K tile: 512 x 16B chunks, swizzled b128 writes ----
#pragma unroll
        for (int cc = 0; cc < 2; ++cc) {
            const int c = t + cc * 256;
            const int row = c >> 3, col8 = c & 7;
            *(bf16x8*)(KsB + row * 128 + ((col8 * 16) ^ SW(row))) =
                *(const bf16x8*)&Kp[(size_t)(key0 + row) * HD + col8 * 8];
        }
        // ---- stage V^T tile: pack 2 keys per b32 write ----
        {
            bf16x8 v0 = *(const bf16x8*)&Vp[(size_t)(key0 + 2 * vp_) * HD + vdb];
            bf16x8 v1 = *(const bf16x8*)&Vp[(size_t)(key0 + 2 * vp_ + 1) * HD + vdb];
#pragma unroll
            for (int i = 0; i < 8; ++i) {
                const int d = vdb + i;
                union { bf16 h2[2]; uint32_t u; } pk;
                pk.h2[0] = v0[i]; pk.h2[1] = v1[i];
                *(uint32_t*)(VtB + d * 128 + ((vp_ * 4) ^ SW(d))) = pk.u;
            }
        }
        __syncthreads();

        // ---- S^T = K Q^T (Q pre-scaled by 1/8) ----
        f32x4 st[4] = {};
#pragma unroll
        for (int kd = 0; kd < 2; ++kd) {
#pragma unroll
            for (int ns = 0; ns < 4; ++ns) {
                const int row = ns * 16 + l15;
                bf16x8 kf = *(const bf16x8*)(KsB + row * 128 +
                                             ((kd * 64 + l4 * 16) ^ SW(row)));
                st[ns] = MFMA16(kf, qf[kd], st[ns]);
            }
        }
        // ---- additive mask: lane's keys are ns*16 + l4*4 + j ----
#pragma unroll
        for (int ns = 0; ns < 4; ++ns) {
            const f32x4 mk = *(const f32x4*)&mkp[key0 + ns * 16 + l4 * 4];
#pragma unroll
            for (int j = 0; j < 4; ++j) st[ns][j] += mk[j];
        }

        // ---- online softmax: lane owns q = q0 + l15; reduce over l4 replicas ----
        float tm = st[0][0];
#pragma unroll
        for (int ns = 0; ns < 4; ++ns)
#pragma unroll
            for (int j = 0; j < 4; ++j) tm = fmaxf(tm, st[ns][j]);
        tm = fmaxf(tm, __shfl_xor(tm, 16));
        tm = fmaxf(tm, __shfl_xor(tm, 32));
        const float mnew = fmaxf(mrun, tm);
        const float sc = __expf(mrun - mnew);
        mrun = mnew;

        uint32_t pk0[4], pk1[4];
        float ps = 0.f;
#pragma unroll
        for (int ns = 0; ns < 4; ++ns) {
            const float p0 = __expf(st[ns][0] - mnew);
            const float p1 = __expf(st[ns][1] - mnew);
            const float p2 = __expf(st[ns][2] - mnew);
            const float p3 = __expf(st[ns][3] - mnew);
            ps += (p0 + p1) + (p2 + p3);
            pk0[ns] = pack_bf16(p0, p1);
            pk1[ns] = pack_bf16(p2, p3);
        }
        ps += __shfl_xor(ps, 16);
        ps += __shfl_xor(ps, 32);
        lrun = lrun * sc + ps;

        // ---- rescale O (pscale lives at lane q; O rows are l4*4+j) ----
        float scj[4];
#pragma unroll
        for (int j = 0; j < 4; ++j) scj[j] = __shfl(sc, l4 * 4 + j);
#pragma unroll
        for (int ds = 0; ds < 4; ++ds)
#pragma unroll
            for (int j = 0; j < 4; ++j) o[ds][j] *= scj[j];

        // ---- build P A-frags (bpermute) and PV ----
#pragma unroll
        for (int ks = 0; ks < 2; ++ks) {
            const uint32_t s00 = __shfl(pk0[2 * ks], src0);
            const uint32_t s10 = __shfl(pk1[2 * ks], src0);
            const uint32_t s01 = __shfl(pk0[2 * ks + 1], src0);
            const uint32_t s11 = __shfl(pk1[2 * ks + 1], src0);
            const uint32_t t00 = __shfl(pk0[2 * ks], src0 + 16);
            const uint32_t t10 = __shfl(pk1[2 * ks], src0 + 16);
            const uint32_t t01 = __shfl(pk0[2 * ks + 1], src0 + 16);
            const uint32_t t11 = __shfl(pk1[2 * ks + 1], src0 + 16);
            union { uint32_t u[4]; bf16x8 v; } pa;
            pa.u[0] = hi ? s01 : s00;
            pa.u[1] = hi ? s11 : s10;
            pa.u[2] = hi ? t01 : t00;
            pa.u[3] = hi ? t11 : t10;
#pragma unroll
            for (int ds = 0; ds < 4; ++ds) {
                const int row = ds * 16 + l15;
                bf16x8 vf = *(const bf16x8*)(VtB + row * 128 +
                                             ((ks * 64 + l4 * 16) ^ SW(row)));
                o[ds] = MFMA16(pa.v, vf, o[ds]);
            }
        }
    }

    // ---- epilogue: O rows q = q0 + l4*4 + j, cols d = ds*16 + l15 ----
    float linv[4];
#pragma unroll
    for (int j = 0; j < 4; ++j) linv[j] = 1.0f / __shfl(lrun, l4 * 4 + j);
#pragma unroll
    for (int ds = 0; ds < 4; ++ds)
#pragma unroll
        for (int j = 0; j < 4; ++j)
            out[(size_t)(b * SS + q0 + l4 * 4 + j) * HID + h * HD + ds * 16 + l15] =
                o[ds][j] * linv[j];
}

// ---------- launch ----------
extern "C" void kernel_launch(void* const* d_in, const int* in_sizes, int n_in,
                              void* d_out, int out_size, void* d_ws, size_t ws_size,
                              hipStream_t stream) {
    (void)in_sizes; (void)n_in; (void)out_size; (void)ws_size;
    const float* hs  = (const float*)d_in[0];
    const float* msk = (const float*)d_in[1];
    const float* Wq  = (const float*)d_in[2];
    const float* bq  = (const float*)d_in[3];
    const float* Wk  = (const float*)d_in[4];
    const float* bk  = (const float*)d_in[5];
    const float* Wv  = (const float*)d_in[6];
    const float* bv  = (const float*)d_in[7];
    float* out = (float*)d_out;
    char* ws = (char*)d_ws;

    bf16* Xb = (bf16*)ws;                          // 8 MB  [4096][1024]
    bf16* Wt = (bf16*)(ws + ((size_t)8 << 20));    // 6 MB  [3072][1024]
    bf16* Qb = (bf16*)(ws + ((size_t)14 << 20));   // 8 MB  [B,H,S,D]
    bf16* Kb = (bf16*)(ws + ((size_t)22 << 20));   // 8 MB
    bf16* Vb = (bf16*)(ws + ((size_t)30 << 20));   // 8 MB

    cvt_hidden<<<dim3(MROW * HID / (256 * 8)), dim3(256), 0, stream>>>(hs, Xb);
    wtrans<<<dim3(32, 32, 3), dim3(32, 8), 0, stream>>>(Wq, Wk, Wv, Wt);
    qkv_gemm<<<dim3(NQKV / 128, MROW / 128), dim3(256), 0, stream>>>(
        Xb, Wt, bq, bk, bv, Qb, Kb, Vb);
    attn_fwd<<<dim3(32 * 32), dim3(256), 0, stream>>>(Qb, Kb, Vb, msk, out);
}